// Round 5
// baseline (544.463 us; speedup 1.0000x reference)
//
#include <hip/hip_runtime.h>
#include <hip/hip_cooperative_groups.h>
#include <cstdint>

namespace cg = cooperative_groups;

// Problem constants
#define BB   8
#define CC   19
#define HWP  524288          // H*W pixels per batch row
#define NPIX 4194304         // B*H*W
#define KSEL 131072          // int(0.25 * HWP)
#define GRID 4096            // blocks for the wide kernels

// ws layout:
//   [0, 16 MiB)  loss float[NPIX]
//   ctrl (u32 words, zeroed via hipMemsetAsync each launch):
#define H1_OFF   0                       // hist1: 8*2048
#define H2_OFF   (8*2048)                // hist2: 8*4096
#define H3_OFF   (H2_OFF + 8*4096)      // hist3: 8*256
#define SEL1_OFF (H3_OFF + 8*256)       // 51200
#define CNT1_OFF (SEL1_OFF + 8)
#define SEL2_OFF (CNT1_OFF + 8)
#define CNT2_OFF (SEL2_OFF + 8)
#define PAD_OFF  (CNT2_OFF + 8)         // pad
#define SUMA_OFF (PAD_OFF + 2)          // byte offset %8==0 -> double-aligned
#define CTRL_WORDS (SUMA_OFF + 16)      // 8 doubles = 16 words
#define LOSS_BYTES (NPIX * 4)

// ---------- block-level primitives (256 threads) ----------

__device__ __forceinline__ uint32_t block_incl_scan_u32(uint32_t v, volatile uint32_t* wt) {
    int lane = threadIdx.x & 63, wid = threadIdx.x >> 6;
    uint32_t inc = v;
#pragma unroll
    for (int off = 1; off < 64; off <<= 1) {
        uint32_t t = __shfl_up(inc, off);
        if (lane >= off) inc += t;
    }
    __syncthreads();                 // protect wt reuse across calls
    if (lane == 63) wt[wid] = inc;
    __syncthreads();
    for (int w = 0; w < wid; w++) inc += wt[w];
    return inc;
}

__device__ __forceinline__ double block_reduce_double(double v, volatile double* dwt) {
    int lane = threadIdx.x & 63, wid = threadIdx.x >> 6;
#pragma unroll
    for (int off = 32; off > 0; off >>= 1) v += __shfl_down(v, off);
    __syncthreads();
    if (lane == 0) dwt[wid] = v;
    __syncthreads();
    return dwt[0] + dwt[1] + dwt[2] + dwt[3];
}

__device__ __forceinline__ void block_sum_atomic(double sum, double* dst, volatile double* dwt) {
    double t = block_reduce_double(sum, dwt);
    if (threadIdx.x == 0 && t != 0.0) atomicAdd(dst, t);
}

// Descending radix-select over one row's NBINS histogram. Every calling block
// computes its row's answer redundantly (8-16KB L2-hot reads) — validated
// across rounds (absmax 0.0). Exactly one thread fires the shared write.
template <int NBINS>
__device__ __forceinline__ void row_select(
    const uint32_t* __restrict__ hrow, uint32_t prev,
    volatile uint32_t* wt, volatile uint32_t* shSel, volatile uint32_t* shCnt,
    uint32_t& sel, uint32_t& cnt)
{
    constexpr int CH = NBINS / 256;
    int base = NBINS - CH * ((int)threadIdx.x + 1);   // thread 0 owns TOP bins
    uint32_t hloc[CH];
    uint32_t csum = 0;
#pragma unroll
    for (int i = 0; i < CH; i++) { hloc[i] = hrow[base + i]; csum += hloc[i]; }
    uint32_t incl = block_incl_scan_u32(csum, wt);
    uint32_t pre = incl - csum;                       // count strictly above my chunk
    uint32_t target = (uint32_t)KSEL - prev;
    if (pre < target && pre + csum >= target) {
        uint32_t cum = pre;
#pragma unroll
        for (int i = CH - 1; i >= 0; i--) {
            uint32_t h = hloc[i];
            if (cum + h >= target) { *shSel = (uint32_t)(base + i); *shCnt = prev + cum; break; }
            cum += h;
        }
    }
    __syncthreads();
    sel = *shSel; cnt = *shCnt;
}

// ---------- K1: fused CE loss + top-12-bit histogram (verified round-0 code) --

__global__ __launch_bounds__(256) void loss_hist1(
    const float* __restrict__ logits, const int* __restrict__ labels,
    float* __restrict__ loss, uint32_t* __restrict__ hist1)
{
    __shared__ uint32_t lh[2048];
    for (int i = threadIdx.x; i < 2048; i += 256) lh[i] = 0u;
    __syncthreads();

    int b = blockIdx.x >> 9;                       // 512 blocks per batch row
    int pix0 = blockIdx.x * 1024 + threadIdx.x * 4;
    int prow = pix0 & (HWP - 1);

    const float4* lg = (const float4*)(logits + (size_t)b * CC * HWP + prow);
    float4 a[CC];
#pragma unroll
    for (int c = 0; c < CC; c++) a[c] = lg[(size_t)c * (HWP / 4)];

    int4 lab = *(const int4*)(labels + pix0);

    float mx0 = a[0].x, mx1 = a[0].y, mx2 = a[0].z, mx3 = a[0].w;
#pragma unroll
    for (int c = 1; c < CC; c++) {
        mx0 = fmaxf(mx0, a[c].x); mx1 = fmaxf(mx1, a[c].y);
        mx2 = fmaxf(mx2, a[c].z); mx3 = fmaxf(mx3, a[c].w);
    }
    float g0 = 0.f, g1 = 0.f, g2 = 0.f, g3 = 0.f;
    float e0 = 0.f, e1 = 0.f, e2 = 0.f, e3 = 0.f;
#pragma unroll
    for (int c = 0; c < CC; c++) {
        e0 += __expf(a[c].x - mx0); e1 += __expf(a[c].y - mx1);
        e2 += __expf(a[c].z - mx2); e3 += __expf(a[c].w - mx3);
        g0 = (lab.x == c) ? a[c].x : g0;
        g1 = (lab.y == c) ? a[c].y : g1;
        g2 = (lab.z == c) ? a[c].z : g2;
        g3 = (lab.w == c) ? a[c].w : g3;
    }
    // CE >= 0 mathematically; clamp guards the bit-histogram from sign-bit flukes.
    float l0 = fmaxf(mx0 + __logf(e0) - g0, 0.f);
    float l1 = fmaxf(mx1 + __logf(e1) - g1, 0.f);
    float l2 = fmaxf(mx2 + __logf(e2) - g2, 0.f);
    float l3 = fmaxf(mx3 + __logf(e3) - g3, 0.f);

    float4 o; o.x = l0; o.y = l1; o.z = l2; o.w = l3;
    *(float4*)(loss + pix0) = o;

    atomicAdd(&lh[__float_as_uint(l0) >> 20], 1u);
    atomicAdd(&lh[__float_as_uint(l1) >> 20], 1u);
    atomicAdd(&lh[__float_as_uint(l2) >> 20], 1u);
    atomicAdd(&lh[__float_as_uint(l3) >> 20], 1u);

    __syncthreads();
    for (int i = threadIdx.x; i < 2048; i += 256) {
        uint32_t v = lh[i];
        if (v) atomicAdd(&hist1[b * 2048 + i], v);
    }
}

// ---------- refine_coop: sel1+refine2 | sel2+refine3 | finalize in ONE kernel.
// Low-VGPR by design (loss values = NG float4 = 4*NG regs held across syncs).
// Loss is read from HBM exactly once; phase-B re-uses registers.

template <int RBLK, int NG>
__global__ __launch_bounds__(256) void refine_coop(
    const float* __restrict__ loss,
    const uint32_t* __restrict__ hist1, uint32_t* __restrict__ hist2,
    uint32_t* __restrict__ hist3,
    uint32_t* __restrict__ sel1g, uint32_t* __restrict__ sel2g,
    uint32_t* __restrict__ cnt2g, double* __restrict__ sumAbove,
    float* __restrict__ out)
{
    cg::grid_group grid = cg::this_grid();
    __shared__ uint32_t lh[4096];
    __shared__ uint32_t wt[4];
    __shared__ double dwt[4];
    __shared__ uint32_t shSel, shCnt;

    const int tid = threadIdx.x;
    const int b = (int)blockIdx.x / RBLK;
    const int rowblk = (int)blockIdx.x % RBLK;

    for (int i = tid; i < 4096; i += 256) lh[i] = 0u;

    // Issue loss loads EARLY so HBM latency hides under the hist1 scan.
    float4 lr[NG];
    const int pbase = b * HWP + rowblk * (1024 * NG) + tid * 4;
#pragma unroll
    for (int g = 0; g < NG; g++)
        lr[g] = *(const float4*)(loss + pbase + g * 1024);

    // ---- phase A: sel1 (redundant per-block) + sum-above + mid-12-bit hist
    uint32_t s1, c1;
    row_select<2048>(hist1 + b * 2048, 0u, wt, &shSel, &shCnt, s1, c1);
    if (rowblk == 0 && tid == 0) sel1g[b] = s1;

    double sum = 0.0;
#pragma unroll
    for (int g = 0; g < NG; g++) {
        float vv[4] = {lr[g].x, lr[g].y, lr[g].z, lr[g].w};
#pragma unroll
        for (int j = 0; j < 4; j++) {
            uint32_t u = __float_as_uint(vv[j]);
            uint32_t t = u >> 20;
            if (t > s1) sum += (double)vv[j];
            else if (t == s1) atomicAdd(&lh[(u >> 8) & 0xFFFu], 1u);
        }
    }
    __syncthreads();
    block_sum_atomic(sum, &sumAbove[b], dwt);
    for (int i = tid; i < 4096; i += 256) {
        uint32_t c = lh[i];
        if (c) atomicAdd(&hist2[b * 4096 + i], c);
    }
    grid.sync();                                   // hist2 complete everywhere

    // ---- phase B: sel2 + sum-above + exact low-8-bit hist (loss from regs)
    uint32_t s2, c2;
    row_select<4096>(hist2 + b * 4096, c1, wt, &shSel, &shCnt, s2, c2);
    if (rowblk == 0 && tid == 0) { sel2g[b] = s2; cnt2g[b] = c2; }
    __syncthreads();
    lh[tid] = 0u;
    __syncthreads();

    double sum2 = 0.0;
#pragma unroll
    for (int g = 0; g < NG; g++) {
        float vv[4] = {lr[g].x, lr[g].y, lr[g].z, lr[g].w};
#pragma unroll
        for (int j = 0; j < 4; j++) {
            uint32_t u = __float_as_uint(vv[j]);
            if ((u >> 20) == s1) {
                uint32_t mid = (u >> 8) & 0xFFFu;
                if (mid > s2) sum2 += (double)vv[j];
                else if (mid == s2) atomicAdd(&lh[u & 0xFFu], 1u);
            }
        }
    }
    __syncthreads();
    block_sum_atomic(sum2, &sumAbove[b], dwt);
    {
        uint32_t c = lh[tid];
        if (c) atomicAdd(&hist3[b * 256 + tid], c);
    }
    grid.sync();                                   // hist3 + sumAbove complete

    // ---- phase C: block 0 finalize (tie-corrected closed-form top-k mean)
    if (blockIdx.x == 0) {
        double tot = 0.0;
        for (int r = 0; r < BB; r++) {
            int b3 = 255 - tid;
            uint32_t h = hist3[r * 256 + b3];
            uint32_t incl = block_incl_scan_u32(h, wt);
            uint32_t pre = incl - h;
            uint32_t rem = (uint32_t)KSEL - cnt2g[r];
            uint32_t take = (rem > pre) ? ((rem - pre < h) ? (rem - pre) : h) : 0u;
            uint32_t P = (sel1g[r] << 20) | (sel2g[r] << 8) | (uint32_t)b3;
            double contrib = (double)take * (double)__uint_as_float(P);
            double s = block_reduce_double(contrib, dwt);
            if (tid == 0) tot += s + sumAbove[r];
        }
        if (tid == 0) out[0] = (float)(tot / ((double)BB * (double)KSEL));
    }
}

// ---------- fallback separate kernels (verified round-4 path) ----------

__global__ __launch_bounds__(256) void refine2s(
    const float* __restrict__ loss, const uint32_t* __restrict__ hist1,
    uint32_t* __restrict__ hist2,
    uint32_t* __restrict__ sel1g, uint32_t* __restrict__ cnt1g,
    double* __restrict__ sumAbove)
{
    __shared__ uint32_t lh[4096];
    __shared__ uint32_t wt[4];
    __shared__ double dwt[4];
    __shared__ uint32_t shSel, shCnt;
    for (int i = threadIdx.x; i < 4096; i += 256) lh[i] = 0u;
    __syncthreads();

    int b = blockIdx.x >> 9;
    int rowblk = blockIdx.x & 511;

    uint32_t s1, c1;
    row_select<2048>(hist1 + b * 2048, 0u, wt, &shSel, &shCnt, s1, c1);
    if (rowblk == 0 && threadIdx.x == 0) { sel1g[b] = s1; cnt1g[b] = c1; }
    __syncthreads();

    int pix0 = blockIdx.x * 1024 + threadIdx.x * 4;
    float4 v = *(const float4*)(loss + pix0);

    double sum = 0.0;
    {
        float vv[4] = {v.x, v.y, v.z, v.w};
#pragma unroll
        for (int j = 0; j < 4; j++) {
            uint32_t u = __float_as_uint(vv[j]);
            uint32_t t = u >> 20;
            if (t > s1) sum += (double)vv[j];
            else if (t == s1) atomicAdd(&lh[(u >> 8) & 0xFFFu], 1u);
        }
    }
    __syncthreads();
    block_sum_atomic(sum, &sumAbove[b], dwt);
    for (int i = threadIdx.x; i < 4096; i += 256) {
        uint32_t c = lh[i];
        if (c) atomicAdd(&hist2[b * 4096 + i], c);
    }
}

__global__ __launch_bounds__(256) void refine3s(
    const float* __restrict__ loss, const uint32_t* __restrict__ hist2,
    uint32_t* __restrict__ hist3,
    const uint32_t* __restrict__ sel1g, const uint32_t* __restrict__ cnt1g,
    uint32_t* __restrict__ sel2g, uint32_t* __restrict__ cnt2g,
    double* __restrict__ sumAbove)
{
    __shared__ uint32_t lh[256];
    __shared__ uint32_t wt[4];
    __shared__ double dwt[4];
    __shared__ uint32_t shSel, shCnt;
    lh[threadIdx.x] = 0u;
    __syncthreads();

    int b = blockIdx.x >> 9;
    int rowblk = blockIdx.x & 511;
    uint32_t s1 = sel1g[b];
    uint32_t c1 = cnt1g[b];

    uint32_t s2, c2;
    row_select<4096>(hist2 + b * 4096, c1, wt, &shSel, &shCnt, s2, c2);
    if (rowblk == 0 && threadIdx.x == 0) { sel2g[b] = s2; cnt2g[b] = c2; }
    __syncthreads();

    int pix0 = blockIdx.x * 1024 + threadIdx.x * 4;
    float4 v = *(const float4*)(loss + pix0);

    double sum = 0.0;
    {
        float vv[4] = {v.x, v.y, v.z, v.w};
#pragma unroll
        for (int j = 0; j < 4; j++) {
            uint32_t u = __float_as_uint(vv[j]);
            if ((u >> 20) == s1) {
                uint32_t mid = (u >> 8) & 0xFFFu;
                if (mid > s2) sum += (double)vv[j];
                else if (mid == s2) atomicAdd(&lh[u & 0xFFu], 1u);
            }
        }
    }
    __syncthreads();
    block_sum_atomic(sum, &sumAbove[b], dwt);
    {
        uint32_t c = lh[threadIdx.x];
        if (c) atomicAdd(&hist3[b * 256 + threadIdx.x], c);
    }
}

__global__ __launch_bounds__(256) void finalize_k(
    const uint32_t* __restrict__ hist3,
    const uint32_t* __restrict__ sel1, const uint32_t* __restrict__ sel2,
    const uint32_t* __restrict__ cnt2, const double* __restrict__ sumAbove,
    float* __restrict__ out)
{
    __shared__ uint32_t wt[4];
    __shared__ double dwt[4];
    double tot = 0.0;
    for (int r = 0; r < BB; r++) {
        int b3 = 255 - (int)threadIdx.x;
        uint32_t h = hist3[r * 256 + b3];
        uint32_t incl = block_incl_scan_u32(h, wt);
        uint32_t pre = incl - h;
        uint32_t rem = (uint32_t)KSEL - cnt2[r];
        uint32_t take = (rem > pre) ? ((rem - pre < h) ? (rem - pre) : h) : 0u;
        uint32_t P = (sel1[r] << 20) | (sel2[r] << 8) | (uint32_t)b3;
        double contrib = (double)take * (double)__uint_as_float(P);
        double s = block_reduce_double(contrib, dwt);
        if (threadIdx.x == 0) tot += s + sumAbove[r];
    }
    if (threadIdx.x == 0) out[0] = (float)(tot / ((double)BB * (double)KSEL));
}

extern "C" void kernel_launch(void* const* d_in, const int* in_sizes, int n_in,
                              void* d_out, int out_size, void* d_ws, size_t ws_size,
                              hipStream_t stream)
{
    const float* logits = (const float*)d_in[0];
    const int* labels   = (const int*)d_in[1];
    float* out          = (float*)d_out;

    char* ws = (char*)d_ws;
    float* loss      = (float*)ws;
    uint32_t* ctrl   = (uint32_t*)(ws + LOSS_BYTES);
    uint32_t* hist1  = ctrl + H1_OFF;
    uint32_t* hist2  = ctrl + H2_OFF;
    uint32_t* hist3  = ctrl + H3_OFF;
    uint32_t* sel1   = ctrl + SEL1_OFF;
    uint32_t* cnt1   = ctrl + CNT1_OFF;
    uint32_t* sel2   = ctrl + SEL2_OFF;
    uint32_t* cnt2   = ctrl + CNT2_OFF;
    double* sumAbove = (double*)(ctrl + SUMA_OFF);

    (void)hipMemsetAsync(ctrl, 0, CTRL_WORDS * sizeof(uint32_t), stream);
    loss_hist1<<<GRID, 256, 0, stream>>>(logits, labels, loss, hist1);

    // Fused refine path: one cooperative kernel (sel1|refine2|sel2|refine3|finalize)
    {
        const float* a0 = loss;
        const uint32_t* a1 = hist1;
        uint32_t* a2 = hist2;
        uint32_t* a3 = hist3;
        uint32_t* a4 = sel1;
        uint32_t* a5 = sel2;
        uint32_t* a6 = cnt2;
        double*   a7 = sumAbove;
        float*    a8 = out;
        void* args[9] = { (void*)&a0, (void*)&a1, (void*)&a2, (void*)&a3,
                          (void*)&a4, (void*)&a5, (void*)&a6, (void*)&a7, (void*)&a8 };

        int nb = 0;
        if (hipOccupancyMaxActiveBlocksPerMultiprocessor(&nb, refine_coop<256, 2>, 256, 0) == hipSuccess
            && nb >= 8) {
            if (hipLaunchCooperativeKernel(refine_coop<256, 2>, dim3(256 * BB), dim3(256),
                                           args, 0, stream) == hipSuccess)
                return;
            (void)hipGetLastError();
        }
        nb = 0;
        if (hipOccupancyMaxActiveBlocksPerMultiprocessor(&nb, refine_coop<128, 4>, 256, 0) == hipSuccess
            && nb >= 4) {
            if (hipLaunchCooperativeKernel(refine_coop<128, 4>, dim3(128 * BB), dim3(256),
                                           args, 0, stream) == hipSuccess)
                return;
            (void)hipGetLastError();
        }
    }

    // Fallback: verified round-4 separate kernels
    refine2s<<<GRID, 256, 0, stream>>>(loss, hist1, hist2, sel1, cnt1, sumAbove);
    refine3s<<<GRID, 256, 0, stream>>>(loss, hist2, hist3, sel1, cnt1, sel2, cnt2, sumAbove);
    finalize_k<<<1, 256, 0, stream>>>(hist3, sel1, sel2, cnt2, sumAbove, out);
}